// Round 4
// baseline (221.794 us; speedup 1.0000x reference)
//
#include <hip/hip_runtime.h>
#include <math.h>

// ---------------- types / helpers ----------------
typedef float f32x4 __attribute__((ext_vector_type(4)));
typedef __bf16 bf16x8 __attribute__((ext_vector_type(8)));
typedef unsigned short ushort_t;

#define MFMA16(a, b, c) __builtin_amdgcn_mfma_f32_16x16x32_bf16((a), (b), (c), 0, 0, 0)

static __device__ __forceinline__ ushort_t f2bf(float f) {
  union { float f; unsigned u; } v; v.f = f;
  unsigned u = v.u;
  return (ushort_t)((u + 0x7FFFu + ((u >> 16) & 1u)) >> 16);  // RNE
}
static __device__ __forceinline__ float bf2f(ushort_t h) {
  union { unsigned u; float f; } v; v.u = ((unsigned)h) << 16;
  return v.f;
}
// async global->LDS, 16B per lane; lds pointer must be wave-uniform (dest = base + lane*16)
static __device__ __forceinline__ void gl_lds16(const void* g, void* lds_uniform) {
  __builtin_amdgcn_global_load_lds(
      (const __attribute__((address_space(1))) unsigned int*)g,
      (__attribute__((address_space(3))) unsigned int*)lds_uniform, 16, 0, 0);
}

// ---------------- fused prep: x/w casts + RoPE table (1 launch) ----------
__global__ void prep(const float* __restrict__ x,
                     const float* __restrict__ wq, const float* __restrict__ wk,
                     const float* __restrict__ wv, const float* __restrict__ wo,
                     ushort_t* __restrict__ Xb, ushort_t* __restrict__ Wqb,
                     ushort_t* __restrict__ Wkb, ushort_t* __restrict__ Wvb,
                     ushort_t* __restrict__ Wob, float2* __restrict__ cs) {
  const int bid = blockIdx.x;
  if (bid < 12288) {
    const float* src;
    ushort_t* dst;
    int i;
    if (bid < 8192) {
      src = x; dst = Xb;
      i = bid * 256 + threadIdx.x;
    } else {
      const int wi = (bid - 8192) >> 10;
      src = (wi == 0) ? wq : (wi == 1) ? wk : (wi == 2) ? wv : wo;
      dst = (wi == 0) ? Wqb : (wi == 1) ? Wkb : (wi == 2) ? Wvb : Wob;
      i = ((bid - 8192) & 1023) * 256 + threadIdx.x;
    }
    f32x4 v = ((const f32x4*)src)[i];
    ushort4 o;
    o.x = f2bf(v.x); o.y = f2bf(v.y); o.z = f2bf(v.z); o.w = f2bf(v.w);
    ((ushort4*)dst)[i] = o;
  } else {
    int idx = (bid - 12288) * 256 + threadIdx.x;  // 4096*32 entries
    int pos = idx >> 5, i = idx & 31;
    double inv = exp2(-(double)i * 0.41524101186092029);  // log2(10000)/32
    double th = (double)pos * inv;
    double s, c;
    sincos(th, &s, &c);
    cs[idx] = make_float2((float)c, (float)s);
  }
}

// ---------------- NT GEMM, BK=64, XOR-swizzled LDS (conflict-free b128 reads) --------
// (R0 proven structure: 128^2 tile, 256 thr / 4 waves, 2-barrier K-loop.)
// C[m][n] = sum_k A[m][k]*W[n][k]. A: MxK bf16 rm, W: NxK bf16 rm.
template <int OUTBF>
__global__ __launch_bounds__(256) void gemm_nt(
    const ushort_t* __restrict__ A, const ushort_t* __restrict__ W,
    void* __restrict__ Cv, int K, int N) {
  __shared__ __align__(16) ushort_t As[128 * 64];
  __shared__ __align__(16) ushort_t Bs[128 * 64];

  const int t = threadIdx.x;
  const int lane = t & 63;
  const int l15 = lane & 15;
  const int quad = lane >> 4;
  const int wave = t >> 6;
  const int wm = wave & 1, wn = wave >> 1;
  const int bm = blockIdx.x, bn = blockIdx.y;

  // staging: thread t -> row t>>3, LDS chunk t&7, global chunk (t&7)^(row&7)
  const int srow = t >> 3;
  const int schunk = (t & 7) ^ (srow & 7);
  const ushort_t* Ag = A + (size_t)(bm * 128 + srow) * K + schunk * 8;
  const ushort_t* Wg = W + (size_t)(bn * 128 + srow) * K + schunk * 8;
  char* AsB = (char*)As + (t & 192) * 16;  // wave-uniform; lane slot = base + lane*16
  char* BsB = (char*)Bs + (t & 192) * 16;
  const size_t rK = (size_t)32 * K;

  const f32x4 zero4 = {0.f, 0.f, 0.f, 0.f};
  f32x4 acc[4][4];
#pragma unroll
  for (int i = 0; i < 4; ++i)
#pragma unroll
    for (int j = 0; j < 4; ++j) acc[i][j] = zero4;

  for (int kt = 0; kt < K; kt += 64) {
#pragma unroll
    for (int p = 0; p < 4; ++p) {
      gl_lds16(Ag + p * rK + kt, AsB + p * 4096);
      gl_lds16(Wg + p * rK + kt, BsB + p * 4096);
    }
    __syncthreads();
#pragma unroll
    for (int ks = 0; ks < 2; ++ks) {
      bf16x8 af[4], bfr[4];
#pragma unroll
      for (int i = 0; i < 4; ++i) {
        const int r = wm * 64 + i * 16 + l15;
        af[i] = *(const bf16x8*)&As[r * 64 + (((ks * 4 + quad) ^ (r & 7)) * 8)];
      }
#pragma unroll
      for (int j = 0; j < 4; ++j) {
        const int r = wn * 64 + j * 16 + l15;
        bfr[j] = *(const bf16x8*)&Bs[r * 64 + (((ks * 4 + quad) ^ (r & 7)) * 8)];
      }
#pragma unroll
      for (int i = 0; i < 4; ++i)
#pragma unroll
        for (int j = 0; j < 4; ++j) acc[i][j] = MFMA16(af[i], bfr[j], acc[i][j]);
    }
    __syncthreads();
  }

  const int rbase = bm * 128 + wm * 64 + quad * 4;
  const int cbase = bn * 128 + wn * 64 + l15;
#pragma unroll
  for (int i = 0; i < 4; ++i)
#pragma unroll
    for (int j = 0; j < 4; ++j)
#pragma unroll
      for (int r = 0; r < 4; ++r) {
        size_t idx = (size_t)(rbase + i * 16 + r) * N + (cbase + j * 16);
        if (OUTBF)
          ((ushort_t*)Cv)[idx] = f2bf(acc[i][j][r]);
        else
          ((float*)Cv)[idx] = acc[i][j][r];
      }
}

// ---------------- fused windowed attention ----------------
static __device__ __forceinline__ void rope8(const ushort_t* __restrict__ g,
                                             ushort_t* __restrict__ lds,
                                             const float2* __restrict__ cs4, float scale) {
  uint4 raw = *(const uint4*)g;
  unsigned rw[4] = {raw.x, raw.y, raw.z, raw.w};
  ushort_t o[8];
#pragma unroll
  for (int m = 0; m < 4; ++m) {
    float x1 = bf2f((ushort_t)(rw[m] & 0xffffu));
    float x2 = bf2f((ushort_t)(rw[m] >> 16));
    float2 sc = cs4[m];
    o[2 * m]     = f2bf((x1 * sc.x - x2 * sc.y) * scale);
    o[2 * m + 1] = f2bf((x1 * sc.y + x2 * sc.x) * scale);
  }
  uint4 w;
  w.x = (unsigned)o[0] | ((unsigned)o[1] << 16);
  w.y = (unsigned)o[2] | ((unsigned)o[3] << 16);
  w.z = (unsigned)o[4] | ((unsigned)o[5] << 16);
  w.w = (unsigned)o[6] | ((unsigned)o[7] << 16);
  *(uint4*)lds = w;  // ds_write_b128
}

__global__ __launch_bounds__(256, 2) void attn(
    const ushort_t* __restrict__ Qb, const ushort_t* __restrict__ Kb,
    const ushort_t* __restrict__ Vb, ushort_t* __restrict__ Yb,
    const float2* __restrict__ cs) {
  __shared__ __align__(16) ushort_t smem[27648];
  ushort_t* Qs = smem;
  ushort_t* Ks = smem + 9216;
  ushort_t* Vt = smem;
  ushort_t* Pc = smem + 16896;

  const int t = threadIdx.x;
  const int lane = t & 63, wave = t >> 6;
  const int l15 = lane & 15, quad = lane >> 4;
  const int win = blockIdx.x >> 1, slice = blockIdx.x & 1;
  const int h = blockIdx.y, b = blockIdx.z;
  const int kBase = win * 256, qBase = kBase + slice * 128;
  const size_t gbase = ((size_t)b * 4096) * 1024 + h * 64;

  const int sr = t >> 3;
  const int c0 = (t & 7) * 8;

#pragma unroll
  for (int p = 0; p < 4; ++p) {
    int r = p * 32 + sr;
    rope8(Qb + gbase + (size_t)(qBase + r) * 1024 + c0, Qs + r * 72 + c0,
          cs + (qBase + r) * 32 + (c0 >> 1), 0.125f);
  }
#pragma unroll
  for (int p = 0; p < 8; ++p) {
    int r = p * 32 + sr;
    rope8(Kb + gbase + (size_t)(kBase + r) * 1024 + c0, Ks + r * 72 + c0,
          cs + (kBase + r) * 32 + (c0 >> 1), 1.0f);
  }
  __syncthreads();

  const int qw = wave * 32;
  const f32x4 zero4 = {0.f, 0.f, 0.f, 0.f};
  f32x4 S[2][16];
#pragma unroll
  for (int i = 0; i < 2; ++i)
#pragma unroll
    for (int j = 0; j < 16; ++j) S[i][j] = zero4;
#pragma unroll
  for (int ks = 0; ks < 2; ++ks) {
    bf16x8 a0 = *(const bf16x8*)&Qs[(qw + l15) * 72 + ks * 32 + quad * 8];
    bf16x8 a1 = *(const bf16x8*)&Qs[(qw + 16 + l15) * 72 + ks * 32 + quad * 8];
#pragma unroll
    for (int j = 0; j < 16; ++j) {
      bf16x8 bk = *(const bf16x8*)&Ks[(j * 16 + l15) * 72 + ks * 32 + quad * 8];
      S[0][j] = MFMA16(a0, bk, S[0][j]);
      S[1][j] = MFMA16(a1, bk, S[1][j]);
    }
  }

  float linv[2][4];
#pragma unroll
  for (int i = 0; i < 2; ++i)
#pragma unroll
    for (int r = 0; r < 4; ++r) {
      float mx = S[i][0][r];
#pragma unroll
      for (int j = 1; j < 16; ++j) mx = fmaxf(mx, S[i][j][r]);
      mx = fmaxf(mx, __shfl_xor(mx, 1));
      mx = fmaxf(mx, __shfl_xor(mx, 2));
      mx = fmaxf(mx, __shfl_xor(mx, 4));
      mx = fmaxf(mx, __shfl_xor(mx, 8));
      float sum = 0.f;
#pragma unroll
      for (int j = 0; j < 16; ++j) {
        float e = __expf(S[i][j][r] - mx);
        S[i][j][r] = e;
        sum += e;
      }
      sum += __shfl_xor(sum, 1);
      sum += __shfl_xor(sum, 2);
      sum += __shfl_xor(sum, 4);
      sum += __shfl_xor(sum, 8);
      linv[i][r] = 1.0f / sum;
    }
  __syncthreads();

#pragma unroll
  for (int p = 0; p < 8; ++p) {
    int k = p * 32 + sr;
    uint4 raw = *(const uint4*)(Vb + gbase + (size_t)(kBase + k) * 1024 + c0);
    ushort_t vv[8];
    vv[0] = raw.x & 0xffffu; vv[1] = raw.x >> 16;
    vv[2] = raw.y & 0xffffu; vv[3] = raw.y >> 16;
    vv[4] = raw.z & 0xffffu; vv[5] = raw.z >> 16;
    vv[6] = raw.w & 0xffffu; vv[7] = raw.w >> 16;
#pragma unroll
    for (int e = 0; e < 8; ++e) {
      int ee = (e + (t & 7)) & 7;
      Vt[(c0 + ee) * 264 + k] = vv[ee];
    }
  }

  auto writeP = [&](int kc) {
#pragma unroll
    for (int i = 0; i < 2; ++i)
#pragma unroll
      for (int jj = 0; jj < 4; ++jj) {
        int j = kc * 4 + jj;
#pragma unroll
        for (int r = 0; r < 4; ++r)
          Pc[(qw + i * 16 + quad * 4 + r) * 72 + jj * 16 + l15] = f2bf(S[i][j][r]);
      }
  };

  writeP(0);
  __syncthreads();

  f32x4 O[2][4];
#pragma unroll
  for (int i = 0; i < 2; ++i)
#pragma unroll
    for (int jd = 0; jd < 4; ++jd) O[i][jd] = zero4;

  for (int kc = 0; kc < 4; ++kc) {
#pragma unroll
    for (int ks = 0; ks < 2; ++ks) {
      bf16x8 a0 = *(const bf16x8*)&Pc[(qw + l15) * 72 + ks * 32 + quad * 8];
      bf16x8 a1 = *(const bf16x8*)&Pc[(qw + 16 + l15) * 72 + ks * 32 + quad * 8];
#pragma unroll
      for (int jd = 0; jd < 4; ++jd) {
        bf16x8 bv = *(const bf16x8*)&Vt[(jd * 16 + l15) * 264 + kc * 64 + ks * 32 + quad * 8];
        O[0][jd] = MFMA16(a0, bv, O[0][jd]);
        O[1][jd] = MFMA16(a1, bv, O[1][jd]);
      }
    }
    if (kc < 3) {
      __syncthreads();
      writeP(kc + 1);
      __syncthreads();
    }
  }

#pragma unroll
  for (int i = 0; i < 2; ++i)
#pragma unroll
    for (int jd = 0; jd < 4; ++jd)
#pragma unroll
      for (int r = 0; r < 4; ++r) {
        int row = qBase + qw + i * 16 + quad * 4 + r;
        int col = jd * 16 + l15;
        Yb[gbase + (size_t)row * 1024 + col] = f2bf(O[i][jd][r] * linv[i][r]);
      }
}

// ---------------- launch ----------------
extern "C" void kernel_launch(void* const* d_in, const int* in_sizes, int n_in,
                              void* d_out, int out_size, void* d_ws, size_t ws_size,
                              hipStream_t stream) {
  (void)in_sizes; (void)n_in; (void)out_size; (void)ws_size;
  const float* x  = (const float*)d_in[0];
  const float* wq = (const float*)d_in[1];
  const float* wk = (const float*)d_in[2];
  const float* wv = (const float*)d_in[3];
  const float* wo = (const float*)d_in[4];

  char* ws = (char*)d_ws;
  // workspace layout (bytes): Xb 16M | Wq..Wo 4x2M | Qb 16M | Kb 16M | Vb 16M | Yb 16M | cs 1M
  ushort_t* Xb  = (ushort_t*)(ws);
  ushort_t* Wqb = (ushort_t*)(ws + 16777216);
  ushort_t* Wkb = Wqb + 1048576;
  ushort_t* Wvb = Wkb + 1048576;
  ushort_t* Wob = Wvb + 1048576;
  ushort_t* Qb  = (ushort_t*)(ws + 25165824);
  ushort_t* Kb  = Qb + 8388608;
  ushort_t* Vb  = Kb + 8388608;
  ushort_t* Yb  = Vb + 8388608;
  float2*   cs  = (float2*)(ws + 92274688);

  prep<<<dim3(12800), dim3(256), 0, stream>>>(x, wq, wk, wv, wo,
                                              Xb, Wqb, Wkb, Wvb, Wob, cs);

  // QKV split into 3 launches (~22 us each) so the top-5 profile surfaces
  // attn / prep / proj with counters (diagnostic for the unaccounted ~140 us).
  gemm_nt<1><<<dim3(64, 8), dim3(256), 0, stream>>>(Xb, Wqb, (void*)Qb, 1024, 1024);
  gemm_nt<1><<<dim3(64, 8), dim3(256), 0, stream>>>(Xb, Wkb, (void*)Kb, 1024, 1024);
  gemm_nt<1><<<dim3(64, 8), dim3(256), 0, stream>>>(Xb, Wvb, (void*)Vb, 1024, 1024);

  attn<<<dim3(32, 16, 2), dim3(256), 0, stream>>>(Qb, Kb, Vb, Yb, cs);

  gemm_nt<0><<<dim3(64, 8), dim3(256), 0, stream>>>(Yb, Wob, d_out, 1024, 1024);
}